// Round 4
// baseline (509.404 us; speedup 1.0000x reference)
//
#include <hip/hip_runtime.h>
#include <cmath>
#include <cstdint>

#define NTOK   16384
#define DM     512
#define NEXP   8
#define LOG100 4.605170185988092f

typedef _Float16 half8  __attribute__((ext_vector_type(8)));
typedef _Float16 half4  __attribute__((ext_vector_type(4)));
typedef float    floatx4 __attribute__((ext_vector_type(4)));

#define MFMA_F16(a, b, c) __builtin_amdgcn_mfma_f32_16x16x32_f16((a), (b), (c), 0, 0, 0)

// async global->LDS, 16B per lane. LDS dest wave-uniform base (HW adds lane*16).
__device__ __forceinline__ void gl_lds16(const void* g, void* l) {
    __builtin_amdgcn_global_load_lds(
        (const __attribute__((address_space(1))) void*)g,
        (__attribute__((address_space(3))) void*)l, 16, 0, 0);
}

// ---------------- ws layout ----------------
// ctrl floats @ws: [0..31] int cnt[2][2][8] | [32..47] imp[2][8] | [48..49] vq[2]
//                  [50..51] tsc[2] | [52..67] ia[2][8] | [128..8319] rmn[16*512]
// @ws+64KB:  float2 wts[2][16384]  (256KB)
// @ws+384KB: float2 bs[2][16384]   (256KB, (best,second) dists)
// @ws+704KB: uchar key[2][2][16384] (64KB)
// @ws+1MB:   w0hi 4MB | w0lo 4MB | w1h 4MB | h16 16MB | bkt(ushort) 2MB  => 31MB total
// xhi/xlo (16MB each) live in d_out's h1 region (dead until layer-1 GEMM).

// =============================== prep ===============================
__global__ __launch_bounds__(256) void prep_kernel(
    const float* __restrict__ rm0, const float* __restrict__ rm1,
    const float* __restrict__ ca0, const float* __restrict__ ca1,
    const float* __restrict__ temp0, const float* __restrict__ temp1,
    float* __restrict__ ctrl, float* __restrict__ rmn)
{
    int tid = threadIdx.x, lane = tid & 63, w = tid >> 6;
    if (tid < 32) ((int*)ctrl)[tid] = 0;                       // cnt
    if (tid >= 32 && tid < 48) ctrl[tid] = 0.f;                // imp
    if (tid == 48 || tid == 49) ctrl[tid] = 0.f;               // vq
    if (tid == 50) ctrl[50] = expf(fminf(temp0[0], LOG100));
    if (tid == 51) ctrl[51] = expf(fminf(temp1[0], LOG100));
    if (tid >= 52 && tid < 68) {
        int i = tid - 52;
        ctrl[tid] = expf(fminf(i < 8 ? ca0[i] : ca1[i - 8], LOG100));
    }
    for (int r = w; r < 16; r += 4) {
        const float* src = (r < 8) ? (rm0 + r * DM) : (rm1 + (r - 8) * DM);
        float v[8]; float ss = 0.f;
        #pragma unroll
        for (int j = 0; j < 8; ++j) { v[j] = src[lane + 64 * j]; ss += v[j] * v[j]; }
        #pragma unroll
        for (int off = 32; off > 0; off >>= 1) ss += __shfl_xor(ss, off);
        float inv = 1.f / fmaxf(sqrtf(ss), 1e-12f);
        float* dst = rmn + r * DM;
        #pragma unroll
        for (int j = 0; j < 8; ++j) dst[lane + 64 * j] = v[j] * inv;
    }
}

// =============================== W conversion (float4-vectorized) ===============================
__global__ __launch_bounds__(256) void conv_w_kernel(
    const float4* __restrict__ W0, const float4* __restrict__ W1,
    half4* __restrict__ w0hi, half4* __restrict__ w0lo, half4* __restrict__ w1h)
{
    int i = blockIdx.x * 256 + threadIdx.x;          // 2048*256 == 2M/4 exactly
    float4 a = W0[i], b = W1[i];
    const float* ap = (const float*)&a;
    const float* bp = (const float*)&b;
    half4 hi, lo, h1;
    #pragma unroll
    for (int j = 0; j < 4; ++j) {
        _Float16 h = (_Float16)ap[j];
        hi[j] = h;
        lo[j] = (_Float16)(ap[j] - (float)h);
        h1[j] = (_Float16)bp[j];
    }
    w0hi[i] = hi; w0lo[i] = lo; w1h[i] = h1;
}

// =============================== routing (1 token / wave, no atomics) ===============================
// Also zeroes this token's output row (zbase) so the GEMM can use atomic accumulate.
__global__ __launch_bounds__(256) void route_kernel(
    const float* __restrict__ src,      // [16384][512]
    const float* __restrict__ rmn,      // [8*512] normalized memory (this layer)
    int relu_in,
    _Float16* __restrict__ dst_hi,      // fp16 hi
    _Float16* __restrict__ dst_lo,      // fp16 lo or nullptr
    float* __restrict__ zbase,          // output region to zero ([16384][512])
    unsigned char* __restrict__ key,    // [2][16384] this layer (slot-major)
    float2* __restrict__ wts,           // [16384] this layer
    float2* __restrict__ bs)            // [16384] this layer (best,second)
{
    __shared__ float rmLds[NEXP * DM];
    int tid = threadIdx.x;
    for (int i = tid; i < NEXP * DM; i += 256) rmLds[i] = rmn[i];
    __syncthreads();
    int lane = tid & 63, w = tid >> 6;
    int token = blockIdx.x * 4 + w;

    const float* row = src + (size_t)token * DM;
    float x[8]; float ss = 0.f;
    #pragma unroll
    for (int j = 0; j < 8; ++j) {
        float v = row[lane + 64 * j];
        if (relu_in) v = fmaxf(v, 0.f);
        x[j] = v; ss += v * v;
    }
    #pragma unroll
    for (int j = 0; j < 8; ++j) {
        _Float16 h = (_Float16)x[j];
        dst_hi[(size_t)token * DM + lane + 64 * j] = h;
        if (dst_lo) dst_lo[(size_t)token * DM + lane + 64 * j] = (_Float16)(x[j] - (float)h);
    }
    // zero output row for atomic-accumulate epilogue
    {
        float4 z = make_float4(0.f, 0.f, 0.f, 0.f);
        float4* zr = (float4*)(zbase + (size_t)token * DM);
        zr[lane * 2] = z;
        zr[lane * 2 + 1] = z;
    }
    float d[8];
    #pragma unroll
    for (int e = 0; e < 8; ++e) {
        float a = 0.f;
        #pragma unroll
        for (int j = 0; j < 8; ++j) a += x[j] * rmLds[e * DM + lane + 64 * j];
        d[e] = a;
    }
    #pragma unroll
    for (int off = 32; off > 0; off >>= 1) {
        ss += __shfl_xor(ss, off);
        #pragma unroll
        for (int e = 0; e < 8; ++e) d[e] += __shfl_xor(d[e], off);
    }
    float inv = 1.f / fmaxf(sqrtf(ss), 1e-12f);
    // top-2 (ties -> lower index, matching lax.top_k)
    float best = -1e30f, second = -1e30f; int be = 0, se = 0;
    #pragma unroll
    for (int e = 0; e < 8; ++e) {
        float de = d[e] * inv;
        if (de > best)        { second = best; se = be; best = de; be = e; }
        else if (de > second) { second = de; se = e; }
    }
    float z = expf(second - best);
    float w0 = 1.f / (1.f + z), w1 = z / (1.f + z);
    if (lane == 0) {
        key[token] = (unsigned char)be;
        key[NTOK + token] = (unsigned char)se;
        wts[token] = make_float2(w0, w1);
        bs[token] = make_float2(best, second);
    }
}

// =============================== bucket compaction ===============================
// 16 blocks: block = slot*8 + e. Deterministic ascending-token compaction via
// ballot/popcount; writes exact count, bucket list, imp (8 atomics), vq (16 atomics).
__global__ __launch_bounds__(256) void compact_kernel(
    const unsigned char* __restrict__ key,  // [2][16384] this layer
    const float2* __restrict__ wts,         // [16384]
    const float2* __restrict__ bs,          // [16384]
    int* __restrict__ cnt,                  // [2][8] this layer
    unsigned short* __restrict__ bkt,       // [2][8][16384] this layer
    float* __restrict__ imp,                // [8] this layer
    float* __restrict__ vq_acc)             // &vq[layer]
{
    int slot = blockIdx.x >> 3, e = blockIdx.x & 7;
    const unsigned char* k = key + slot * NTOK;
    unsigned short* ob = bkt + (size_t)(slot * 8 + e) * NTOK;
    __shared__ int wc[2][4];
    int tid = threadIdx.x, lane = tid & 63, w = tid >> 6;
    int base = 0;
    float wsum = 0.f, vqs = 0.f;
    for (int c = 0; c < 64; ++c) {
        int tok = c * 256 + tid;
        bool m = (k[tok] == (unsigned char)e);
        unsigned long long mask = __ballot(m);
        int p = c & 1;
        if (lane == 0) wc[p][w] = __popcll(mask);
        __syncthreads();
        int off = base;
        for (int i = 0; i < w; ++i) off += wc[p][i];
        if (m) {
            int pre = __popcll(mask & ((1ull << lane) - 1ull));
            ob[off + pre] = (unsigned short)tok;
            float2 wp = wts[tok]; float2 b2 = bs[tok];
            float wv = slot ? wp.y : wp.x;
            wsum += wv;
            vqs  += wv * (slot ? b2.y : b2.x);
        }
        base += wc[p][0] + wc[p][1] + wc[p][2] + wc[p][3];
    }
    #pragma unroll
    for (int off = 32; off > 0; off >>= 1) {
        wsum += __shfl_xor(wsum, off);
        vqs  += __shfl_xor(vqs, off);
    }
    __shared__ float rw[4], rv[4];
    if (lane == 0) { rw[w] = wsum; rv[w] = vqs; }
    __syncthreads();
    if (tid == 0) {
        cnt[slot * 8 + e] = base;
        float W = rw[0] + rw[1] + rw[2] + rw[3];
        float V = rv[0] + rv[1] + rv[2] + rv[3];
        atomicAdd(&imp[e], W);
        atomicAdd(vq_acc, -V);
    }
}

// =============================== grouped GEMM (slot-fused, atomic epilogue) ===============================
// 128x128 tile, 4 waves (2x2 of 64x64), 16x16x32 f16 MFMA.
// grid.x = 8*2*4*128: bx -> e = bx&7 (XCD pin: all of expert e on XCD e),
// then n0 (fastest: 4 n-siblings adjacent in dispatch -> A-tile L2 reuse),
// then slot, then mt. Output rows pre-zeroed; epilogue = unsafeAtomicAdd
// (exactly 2 commutative fadds per element -> deterministic).
// LDS: [128 rows][64 halves], 8 chunks of 8 halves/row, XOR-swizzled p=c^(row&7).
// SPLIT: chunks 0-3 = hi(k0..31), 4-7 = lo(k0..31), KSTEP=32. Plain: 64 k's.
template <bool SPLIT>
__global__ __launch_bounds__(256) void gemm_kernel(
    const _Float16* __restrict__ Ahi, const _Float16* __restrict__ Alo,
    const _Float16* __restrict__ Whi, const _Float16* __restrict__ Wlo,
    const float* __restrict__ bias,   // [8][512]
    const float* __restrict__ iav,    // [8]
    const float* __restrict__ tscp,
    const int* __restrict__ cnt,      // [2][8] this layer
    const unsigned short* __restrict__ bkt, // [2][8][16384] this layer
    const float2* __restrict__ wts,   // [16384]
    float* __restrict__ outp)
{
    __shared__ __align__(16) _Float16 lds[2 * 128 * 64];
    __shared__ int tokLds[128];
    _Float16* tA = lds;
    _Float16* tB = lds + 128 * 64;

    int bx = blockIdx.x;
    int e = bx & 7; int r = bx >> 3;
    int n0 = (r & 3) << 7; r >>= 2;
    int slot = r & 1; int mt = r >> 1;
    int M = cnt[slot * 8 + e];
    int m0 = mt << 7;
    if (m0 >= M) return;
    int valid = min(128, M - m0);
    int tid = threadIdx.x, lane = tid & 63, w = tid >> 6;
    const unsigned short* ob = bkt + (size_t)(slot * 8 + e) * NTOK;
    if (tid < 128) tokLds[tid] = ob[m0 + min(tid, valid - 1)];
    __syncthreads();

    floatx4 acc[4][4];
    #pragma unroll
    for (int mi = 0; mi < 4; ++mi)
        #pragma unroll
        for (int ni = 0; ni < 4; ++ni) acc[mi][ni] = (floatx4){0.f, 0.f, 0.f, 0.f};

    const _Float16* WbH = Whi + ((size_t)e * DM + n0) * DM;
    const _Float16* WbL = SPLIT ? (Wlo + ((size_t)e * DM + n0) * DM) : nullptr;

    int subRow = lane >> 3, p = lane & 7;
    int cSt = p ^ (subRow & 7);
    int wm = w >> 1, wn = w & 1;
    int r0 = wm * 64, c0 = wn * 64;
    int q = lane >> 4, l15 = lane & 15;

    constexpr int KIT = SPLIT ? 16 : 8;
    constexpr int KSTEP = SPLIT ? 32 : 64;

    // K-invariant staging state: global src pointers (advance by KSTEP) + LDS dests
    const _Float16* aPtr[4]; const _Float16* bPtr[4];
    _Float16* aDst[4]; _Float16* bDst[4];
    #pragma unroll
    for (int jj = 0; jj < 4; ++jj) {
        int j = w + jj * 4;
        int row = j * 8 + subRow;
        int tok = tokLds[row];
        if constexpr (SPLIT) {
            aPtr[jj] = (cSt < 4) ? (Ahi + (size_t)tok * DM + cSt * 8)
                                 : (Alo + (size_t)tok * DM + (cSt - 4) * 8);
            bPtr[jj] = (cSt < 4) ? (WbH + (size_t)row * DM + cSt * 8)
                                 : (WbL + (size_t)row * DM + (cSt - 4) * 8);
        } else {
            aPtr[jj] = Ahi + (size_t)tok * DM + cSt * 8;
            bPtr[jj] = WbH + (size_t)row * DM + cSt * 8;
        }
        aDst[jj] = tA + j * 512;
        bDst[jj] = tB + j * 512;
    }
    // K-invariant LDS fragment pointers
    const half8 *aHp[4], *aLp[4], *bHp[4], *bLp[4];
    #pragma unroll
    for (int i = 0; i < 4; ++i) {
        int ra = r0 + i * 16 + l15;
        int rb = c0 + i * 16 + l15;
        if constexpr (SPLIT) {
            aHp[i] = (const half8*)(tA + ra * 64 + ((q) ^ (ra & 7)) * 8);
            aLp[i] = (const half8*)(tA + ra * 64 + ((q + 4) ^ (ra & 7)) * 8);
            bHp[i] = (const half8*)(tB + rb * 64 + ((q) ^ (rb & 7)) * 8);
            bLp[i] = (const half8*)(tB + rb * 64 + ((q + 4) ^ (rb & 7)) * 8);
        } else {
            aHp[i] = (const half8*)(tA + ra * 64 + ((q) ^ (ra & 7)) * 8);
            aLp[i] = (const half8*)(tA + ra * 64 + ((4 + q) ^ (ra & 7)) * 8);
            bHp[i] = (const half8*)(tB + rb * 64 + ((q) ^ (rb & 7)) * 8);
            bLp[i] = (const half8*)(tB + rb * 64 + ((4 + q) ^ (rb & 7)) * 8);
        }
    }

    for (int kb = 0; kb < KIT; ++kb) {
        #pragma unroll
        for (int jj = 0; jj < 4; ++jj) {
            gl_lds16(aPtr[jj], (void*)aDst[jj]);
            aPtr[jj] += KSTEP;
        }
        #pragma unroll
        for (int jj = 0; jj < 4; ++jj) {
            gl_lds16(bPtr[jj], (void*)bDst[jj]);
            bPtr[jj] += KSTEP;
        }
        __syncthreads();

        if constexpr (SPLIT) {
            half8 ah[4], al[4];
            #pragma unroll
            for (int mi = 0; mi < 4; ++mi) { ah[mi] = *aHp[mi]; al[mi] = *aLp[mi]; }
            #pragma unroll
            for (int ni = 0; ni < 4; ++ni) {
                half8 bh = *bHp[ni];
                half8 bl = *bLp[ni];
                #pragma unroll
                for (int mi = 0; mi < 4; ++mi) acc[mi][ni] = MFMA_F16(ah[mi], bh, acc[mi][ni]);
                #pragma unroll
                for (int mi = 0; mi < 4; ++mi) acc[mi][ni] = MFMA_F16(ah[mi], bl, acc[mi][ni]);
                #pragma unroll
                for (int mi = 0; mi < 4; ++mi) acc[mi][ni] = MFMA_F16(al[mi], bh, acc[mi][ni]);
            }
        } else {
            // two K-substeps: chunks 0-3 then 4-7
            half8 a[4];
            #pragma unroll
            for (int mi = 0; mi < 4; ++mi) a[mi] = *aHp[mi];
            #pragma unroll
            for (int ni = 0; ni < 4; ++ni) {
                half8 b = *bHp[ni];
                #pragma unroll
                for (int mi = 0; mi < 4; ++mi) acc[mi][ni] = MFMA_F16(a[mi], b, acc[mi][ni]);
            }
            #pragma unroll
            for (int mi = 0; mi < 4; ++mi) a[mi] = *aLp[mi];
            #pragma unroll
            for (int ni = 0; ni < 4; ++ni) {
                half8 b = *bLp[ni];
                #pragma unroll
                for (int mi = 0; mi < 4; ++mi) acc[mi][ni] = MFMA_F16(a[mi], b, acc[mi][ni]);
            }
        }
        __syncthreads();
    }

    // epilogue: C/D layout col=lane&15, row=(lane>>4)*4+reg; atomic accumulate
    float t = *tscp, iae = iav[e];
    float bv[4];
    #pragma unroll
    for (int ni = 0; ni < 4; ++ni) bv[ni] = bias[e * DM + n0 + c0 + ni * 16 + l15];
    #pragma unroll
    for (int mi = 0; mi < 4; ++mi) {
        int liBase = r0 + mi * 16 + q * 4;
        #pragma unroll
        for (int reg = 0; reg < 4; ++reg) {
            int li = liBase + reg;
            if (li < valid) {
                int tok = tokLds[li];
                float2 wp = wts[tok];
                float wgt = slot ? wp.y : wp.x;
                float sg = t * wgt * iae, sb = t * wgt;
                float* orow = outp + (size_t)tok * DM + n0;
                #pragma unroll
                for (int ni = 0; ni < 4; ++ni) {
                    float v = acc[mi][ni][reg] * sg + bv[ni] * sb;
                    int c = c0 + ni * 16 + l15;
                    unsafeAtomicAdd(&orow[c], v);
                }
            }
        }
    }
}

// =============================== finalize aux ===============================
__global__ void finalize_kernel(const float* __restrict__ ctrl, float* __restrict__ outp)
{
    if (threadIdx.x == 0) {
        float aux = 0.f;
        for (int l = 0; l < 2; ++l) {
            float vq = ctrl[48 + l] / (float)NTOK;
            float mean = 0.f;
            for (int e = 0; e < 8; ++e) mean += ctrl[32 + l * 8 + e];
            mean *= 0.125f;
            float s = 0.f;
            for (int e = 0; e < 8; ++e) {
                float d = ctrl[32 + l * 8 + e] - mean;
                s += d * d;
            }
            float var = s / 7.f;                       // ddof=1
            float lb = var / (mean * mean + 1e-10f);
            aux += 0.05f * vq + 0.01f * lb;
        }
        *outp = aux;
    }
}

// =============================== launch ===============================
extern "C" void kernel_launch(void* const* d_in, const int* in_sizes, int n_in,
                              void* d_out, int out_size, void* d_ws, size_t ws_size,
                              hipStream_t stream) {
    const float* x     = (const float*)d_in[0];
    const float* rm0   = (const float*)d_in[1];
    const float* W0    = (const float*)d_in[2];
    const float* b0    = (const float*)d_in[3];
    const float* temp0 = (const float*)d_in[4];
    const float* ca0   = (const float*)d_in[5];
    const float* rm1   = (const float*)d_in[6];
    const float* W1    = (const float*)d_in[7];
    const float* b1    = (const float*)d_in[8];
    const float* temp1 = (const float*)d_in[9];
    const float* ca1   = (const float*)d_in[10];
    float* out = (float*)d_out;

    char* ws = (char*)d_ws;
    float* ctrl = (float*)ws;
    int*   cnt  = (int*)ctrl;                 // [2][2][8]
    float* imp  = ctrl + 32;                  // [2][8]
    float* vq   = ctrl + 48;                  // [2]
    float* tsc  = ctrl + 50;                  // [2]
    float* ia   = ctrl + 52;                  // [2][8]
    float* rmn  = ctrl + 128;                 // [16][512]
    float2*        wts = (float2*)(ws + (size_t)64  * 1024);  // [2][16384]
    float2*        bs  = (float2*)(ws + (size_t)384 * 1024);  // [2][16384]
    unsigned char* key = (unsigned char*)(ws + (size_t)704 * 1024); // [2][2][16384]

    char* big = ws + (1 << 20);
    half4*          w0hi4 = (half4*)(big);                                 // 4MB
    half4*          w0lo4 = (half4*)(big + (size_t)4  * 1024 * 1024);      // 4MB
    half4*          w1h4  = (half4*)(big + (size_t)8  * 1024 * 1024);      // 4MB
    _Float16*       w0hi  = (_Float16*)w0hi4;
    _Float16*       w0lo  = (_Float16*)w0lo4;
    _Float16*       w1h   = (_Float16*)w1h4;
    _Float16*       h16   = (_Float16*)(big + (size_t)12 * 1024 * 1024);   // 16MB
    unsigned short* bkt   = (unsigned short*)(big + (size_t)28 * 1024 * 1024); // 2MB
    // total ws use: 31MB

    // xhi/xlo live in d_out's h1 region (32MB), dead until layer-1 GEMM
    _Float16* xhi = (_Float16*)(out + (size_t)NTOK * DM);
    _Float16* xlo = xhi + (size_t)NTOK * DM;
    float* h0 = out;
    float* h1 = out + (size_t)NTOK * DM;

    prep_kernel<<<1, 256, 0, stream>>>(rm0, rm1, ca0, ca1, temp0, temp1, ctrl, rmn);
    conv_w_kernel<<<2048, 256, 0, stream>>>((const float4*)W0, (const float4*)W1,
                                            w0hi4, w0lo4, w1h4);

    // layer 0: route (+zero h0) -> compact -> slot-fused split GEMM (atomic)
    route_kernel<<<4096, 256, 0, stream>>>(x, rmn, 0, xhi, xlo, h0,
        key, wts, bs);
    compact_kernel<<<16, 256, 0, stream>>>(key, wts, bs, cnt, bkt, imp, vq);
    gemm_kernel<true><<<8192, 256, 0, stream>>>(xhi, xlo, w0hi, w0lo, b0, ia, tsc,
        cnt, bkt, wts, h0);

    // layer 1: route on h0 (relu + h->fp16 fused, zeroes h1 over dead xhi/xlo)
    route_kernel<<<4096, 256, 0, stream>>>(h0, rmn + 4096, 1, h16, (_Float16*)nullptr, h1,
        key + 2 * NTOK, wts + NTOK, bs + NTOK);
    compact_kernel<<<16, 256, 0, stream>>>(key + 2 * NTOK, wts + NTOK, bs + NTOK,
        cnt + 16, bkt + 16 * NTOK, imp + 8, vq + 1);
    gemm_kernel<false><<<8192, 256, 0, stream>>>(h16, (const _Float16*)nullptr, w1h,
        (const _Float16*)nullptr, b1, ia + 8, tsc + 1,
        cnt + 16, bkt + 16 * NTOK, wts + NTOK, h1);

    finalize_kernel<<<1, 64, 0, stream>>>(ctrl, out + (size_t)2 * NTOK * DM);
}

// Round 5
// 506.990 us; speedup vs baseline: 1.0048x; 1.0048x over previous
//
#include <hip/hip_runtime.h>
#include <cmath>
#include <cstdint>

#define NTOK   16384
#define DM     512
#define NEXP   8
#define LOG100 4.605170185988092f

typedef _Float16 half8  __attribute__((ext_vector_type(8)));
typedef _Float16 half4  __attribute__((ext_vector_type(4)));
typedef float    floatx4 __attribute__((ext_vector_type(4)));

#define MFMA_F16(a, b, c) __builtin_amdgcn_mfma_f32_16x16x32_f16((a), (b), (c), 0, 0, 0)

// async global->LDS, 16B per lane. LDS dest wave-uniform base (HW adds lane*16).
__device__ __forceinline__ void gl_lds16(const void* g, void* l) {
    __builtin_amdgcn_global_load_lds(
        (const __attribute__((address_space(1))) void*)g,
        (__attribute__((address_space(3))) void*)l, 16, 0, 0);
}

// ---------------- ws layout (15MB total, proven-safe region) ----------------
// ctrl floats @ws: [0..31] int cnt[2][2][8] | [32..47] imp[2][8] | [48..49] vq[2]
//                  [50..51] tsc[2] | [52..67] ia[2][8] | [128..8319] rmn[16*512]
// @ws+64KB:  float2 wts[2][16384]  (256KB)
// @ws+384KB: float2 bs[2][16384]   (256KB)
// @ws+704KB: uchar key[2][2][16384] (64KB)
// @ws+1MB:   w0hi 4MB | w0lo 4MB | w1h 4MB | bkt(ushort) 2MB
// d_out: h0 region = s0 then h_emb; h1 region = s1 then h1. No other aliases.

// =============================== prep ===============================
__global__ __launch_bounds__(256) void prep_kernel(
    const float* __restrict__ rm0, const float* __restrict__ rm1,
    const float* __restrict__ ca0, const float* __restrict__ ca1,
    const float* __restrict__ temp0, const float* __restrict__ temp1,
    float* __restrict__ ctrl, float* __restrict__ rmn)
{
    int tid = threadIdx.x, lane = tid & 63, w = tid >> 6;
    if (tid < 32) ((int*)ctrl)[tid] = 0;                       // cnt
    if (tid >= 32 && tid < 48) ctrl[tid] = 0.f;                // imp
    if (tid == 48 || tid == 49) ctrl[tid] = 0.f;               // vq
    if (tid == 50) ctrl[50] = expf(fminf(temp0[0], LOG100));
    if (tid == 51) ctrl[51] = expf(fminf(temp1[0], LOG100));
    if (tid >= 52 && tid < 68) {
        int i = tid - 52;
        ctrl[tid] = expf(fminf(i < 8 ? ca0[i] : ca1[i - 8], LOG100));
    }
    for (int r = w; r < 16; r += 4) {
        const float* src = (r < 8) ? (rm0 + r * DM) : (rm1 + (r - 8) * DM);
        float v[8]; float ss = 0.f;
        #pragma unroll
        for (int j = 0; j < 8; ++j) { v[j] = src[lane + 64 * j]; ss += v[j] * v[j]; }
        #pragma unroll
        for (int off = 32; off > 0; off >>= 1) ss += __shfl_xor(ss, off);
        float inv = 1.f / fmaxf(sqrtf(ss), 1e-12f);
        float* dst = rmn + r * DM;
        #pragma unroll
        for (int j = 0; j < 8; ++j) dst[lane + 64 * j] = v[j] * inv;
    }
}

// =============================== W conversion ===============================
__global__ __launch_bounds__(256) void conv_w_kernel(
    const float4* __restrict__ W0, const float4* __restrict__ W1,
    half4* __restrict__ w0hi, half4* __restrict__ w0lo, half4* __restrict__ w1h)
{
    int i = blockIdx.x * 256 + threadIdx.x;          // 2048*256 == 2M/4 exactly
    float4 a = W0[i], b = W1[i];
    const float* ap = (const float*)&a;
    const float* bp = (const float*)&b;
    half4 hi, lo, h1;
    #pragma unroll
    for (int j = 0; j < 4; ++j) {
        _Float16 h = (_Float16)ap[j];
        hi[j] = h;
        lo[j] = (_Float16)(ap[j] - (float)h);
        h1[j] = (_Float16)bp[j];
    }
    w0hi[i] = hi; w0lo[i] = lo; w1h[i] = h1;
}

// =============================== routing layer 0 ===============================
__global__ __launch_bounds__(256) void route0_kernel(
    const float* __restrict__ src, const float* __restrict__ rmn,
    unsigned char* __restrict__ key, float2* __restrict__ wts, float2* __restrict__ bs)
{
    __shared__ float rmLds[NEXP * DM];
    int tid = threadIdx.x;
    for (int i = tid; i < NEXP * DM; i += 256) rmLds[i] = rmn[i];
    __syncthreads();
    int lane = tid & 63, w = tid >> 6;
    int token = blockIdx.x * 4 + w;

    const float* row = src + (size_t)token * DM;
    float x[8]; float ss = 0.f;
    #pragma unroll
    for (int j = 0; j < 8; ++j) { float v = row[lane + 64 * j]; x[j] = v; ss += v * v; }
    float d[8];
    #pragma unroll
    for (int e = 0; e < 8; ++e) {
        float a = 0.f;
        #pragma unroll
        for (int j = 0; j < 8; ++j) a += x[j] * rmLds[e * DM + lane + 64 * j];
        d[e] = a;
    }
    #pragma unroll
    for (int off = 32; off > 0; off >>= 1) {
        ss += __shfl_xor(ss, off);
        #pragma unroll
        for (int e = 0; e < 8; ++e) d[e] += __shfl_xor(d[e], off);
    }
    float inv = 1.f / fmaxf(sqrtf(ss), 1e-12f);
    float best = -1e30f, second = -1e30f; int be = 0, se = 0;
    #pragma unroll
    for (int e = 0; e < 8; ++e) {
        float de = d[e] * inv;
        if (de > best)        { second = best; se = be; best = de; be = e; }
        else if (de > second) { second = de; se = e; }
    }
    float z = expf(second - best);
    float w0 = 1.f / (1.f + z), w1 = z / (1.f + z);
    if (lane == 0) {
        key[token] = (unsigned char)be;
        key[NTOK + token] = (unsigned char)se;
        wts[token] = make_float2(w0, w1);
        bs[token] = make_float2(best, second);
    }
}

// =============================== routing layer 1 (+combine s0+s1 -> h_emb) ===============================
__global__ __launch_bounds__(256) void route1_kernel(
    const float* s0, const float* s1, float* hemb,   // hemb aliases s0 (in-place)
    const float* __restrict__ rmn,
    unsigned char* __restrict__ key, float2* __restrict__ wts, float2* __restrict__ bs)
{
    __shared__ float rmLds[NEXP * DM];
    int tid = threadIdx.x;
    for (int i = tid; i < NEXP * DM; i += 256) rmLds[i] = rmn[i];
    __syncthreads();
    int lane = tid & 63, w = tid >> 6;
    int token = blockIdx.x * 4 + w;

    float x[8]; float ss = 0.f;
    #pragma unroll
    for (int j = 0; j < 8; ++j) {
        size_t idx = (size_t)token * DM + lane + 64 * j;
        float v = s0[idx] + s1[idx];
        hemb[idx] = v;                       // h_emb output (pre-activation)
        float r = fmaxf(v, 0.f);
        x[j] = r; ss += r * r;
    }
    float d[8];
    #pragma unroll
    for (int e = 0; e < 8; ++e) {
        float a = 0.f;
        #pragma unroll
        for (int j = 0; j < 8; ++j) a += x[j] * rmLds[e * DM + lane + 64 * j];
        d[e] = a;
    }
    #pragma unroll
    for (int off = 32; off > 0; off >>= 1) {
        ss += __shfl_xor(ss, off);
        #pragma unroll
        for (int e = 0; e < 8; ++e) d[e] += __shfl_xor(d[e], off);
    }
    float inv = 1.f / fmaxf(sqrtf(ss), 1e-12f);
    float best = -1e30f, second = -1e30f; int be = 0, se = 0;
    #pragma unroll
    for (int e = 0; e < 8; ++e) {
        float de = d[e] * inv;
        if (de > best)        { second = best; se = be; best = de; be = e; }
        else if (de > second) { second = de; se = e; }
    }
    float z = expf(second - best);
    float w0 = 1.f / (1.f + z), w1 = z / (1.f + z);
    if (lane == 0) {
        key[token] = (unsigned char)be;
        key[NTOK + token] = (unsigned char)se;
        wts[token] = make_float2(w0, w1);
        bs[token] = make_float2(best, second);
    }
}

// =============================== bucket compaction ===============================
__global__ __launch_bounds__(256) void compact_kernel(
    const unsigned char* __restrict__ key, const float2* __restrict__ wts,
    const float2* __restrict__ bs, int* __restrict__ cnt,
    unsigned short* __restrict__ bkt, float* __restrict__ imp, float* __restrict__ vq_acc)
{
    int slot = blockIdx.x >> 3, e = blockIdx.x & 7;
    const unsigned char* k = key + slot * NTOK;
    unsigned short* ob = bkt + (size_t)(slot * 8 + e) * NTOK;
    __shared__ int wc[2][4];
    int tid = threadIdx.x, lane = tid & 63, w = tid >> 6;
    int base = 0;
    float wsum = 0.f, vqs = 0.f;
    for (int c = 0; c < 64; ++c) {
        int tok = c * 256 + tid;
        bool m = (k[tok] == (unsigned char)e);
        unsigned long long mask = __ballot(m);
        int p = c & 1;
        if (lane == 0) wc[p][w] = __popcll(mask);
        __syncthreads();
        int off = base;
        for (int i = 0; i < w; ++i) off += wc[p][i];
        if (m) {
            int pre = __popcll(mask & ((1ull << lane) - 1ull));
            ob[off + pre] = (unsigned short)tok;
            float2 wp = wts[tok]; float2 b2 = bs[tok];
            float wv = slot ? wp.y : wp.x;
            wsum += wv;
            vqs  += wv * (slot ? b2.y : b2.x);
        }
        base += wc[p][0] + wc[p][1] + wc[p][2] + wc[p][3];
    }
    #pragma unroll
    for (int off = 32; off > 0; off >>= 1) {
        wsum += __shfl_xor(wsum, off);
        vqs  += __shfl_xor(vqs, off);
    }
    __shared__ float rw[4], rv[4];
    if (lane == 0) { rw[w] = wsum; rv[w] = vqs; }
    __syncthreads();
    if (tid == 0) {
        cnt[slot * 8 + e] = base;
        atomicAdd(&imp[e], rw[0] + rw[1] + rw[2] + rw[3]);
        atomicAdd(vq_acc, -(rv[0] + rv[1] + rv[2] + rv[3]));
    }
}

// =============================== layer-0 GEMM (split-fp16, slot-fused) ===============================
// 64x64 tile, 4 waves (2x2 of 32x32). A staged on-the-fly from fp32 x (hi/lo split),
// B via gl_lds16 from preconverted w0hi/w0lo. KSTEP=32, KIT=16.
// LDS rows: 64 halves = 8 chunks of 8, swizzled pos = chunk ^ (row&7).
// bx: e=bx&7 (XCD pin), nIdx=(bx>>3)&7, slot=(bx>>6)&1, mt=bx>>7.
__global__ __launch_bounds__(256) void gemm0_kernel(
    const float* __restrict__ x,
    const _Float16* __restrict__ Whi, const _Float16* __restrict__ Wlo,
    const float* __restrict__ bias, const float* __restrict__ iav,
    const float* __restrict__ tscp,
    const int* __restrict__ cnt, const unsigned short* __restrict__ bkt,
    const float2* __restrict__ wts,
    float* __restrict__ s0, float* __restrict__ s1)
{
    __shared__ __align__(16) _Float16 tA[64 * 64];
    __shared__ __align__(16) _Float16 tB[64 * 64];
    __shared__ int tokLds[64];

    int bx = blockIdx.x;
    int e = bx & 7, nIdx = (bx >> 3) & 7, slot = (bx >> 6) & 1, mt = bx >> 7;
    int M = cnt[slot * 8 + e];
    int m0 = mt << 6;
    if (m0 >= M) return;
    int n0 = nIdx << 6;
    int valid = min(64, M - m0);
    int tid = threadIdx.x, lane = tid & 63, w = tid >> 6;
    const unsigned short* ob = bkt + (size_t)(slot * 8 + e) * NTOK;
    if (tid < 64) tokLds[tid] = ob[m0 + min(tid, valid - 1)];
    __syncthreads();

    floatx4 acc[2][2];
    #pragma unroll
    for (int mi = 0; mi < 2; ++mi)
        #pragma unroll
        for (int ni = 0; ni < 2; ++ni) acc[mi][ni] = (floatx4){0.f, 0.f, 0.f, 0.f};

    const _Float16* WbH = Whi + ((size_t)e * DM + n0) * DM;
    const _Float16* WbL = Wlo + ((size_t)e * DM + n0) * DM;

    // B staging: 2 gl_lds16 per thread per iter
    int subRow = lane >> 3, p = lane & 7;
    int cSt = p ^ (subRow & 7);
    const _Float16* bPtr[2]; _Float16* bDst[2];
    #pragma unroll
    for (int jj = 0; jj < 2; ++jj) {
        int j = w + jj * 4;
        int row = j * 8 + subRow;
        bPtr[jj] = (cSt < 4) ? (WbH + (size_t)row * DM + cSt * 8)
                             : (WbL + (size_t)row * DM + (cSt - 4) * 8);
        bDst[jj] = tB + j * 512;
    }
    // A staging: thread -> (row ar, k-chunk kc); 2 float4 loads -> hi8+lo8 ds_write_b128
    int ar = tid >> 2, kc = tid & 3;
    const float4* aBase = (const float4*)(x + (size_t)tokLds[ar] * DM);
    _Float16* aDstHi = tA + ar * 64 + ((kc)     ^ (ar & 7)) * 8;
    _Float16* aDstLo = tA + ar * 64 + ((kc + 4) ^ (ar & 7)) * 8;

    // fragment pointers (wave tile 32x32 at r0,c0)
    int wm = w >> 1, wn = w & 1;
    int r0 = wm * 32, c0 = wn * 32;
    int q = lane >> 4, l15 = lane & 15;
    const half8 *aHp[2], *aLp[2], *bHp[2], *bLp[2];
    #pragma unroll
    for (int i = 0; i < 2; ++i) {
        int ra = r0 + i * 16 + l15;
        aHp[i] = (const half8*)(tA + ra * 64 + ((q)     ^ (ra & 7)) * 8);
        aLp[i] = (const half8*)(tA + ra * 64 + ((q + 4) ^ (ra & 7)) * 8);
        int rb = c0 + i * 16 + l15;
        bHp[i] = (const half8*)(tB + rb * 64 + ((q)     ^ (rb & 7)) * 8);
        bLp[i] = (const half8*)(tB + rb * 64 + ((q + 4) ^ (rb & 7)) * 8);
    }

    float4 pf0 = aBase[kc * 2], pf1 = aBase[kc * 2 + 1];
    for (int kb = 0; kb < 16; ++kb) {
        // convert + write A
        float fv[8] = {pf0.x, pf0.y, pf0.z, pf0.w, pf1.x, pf1.y, pf1.z, pf1.w};
        half8 hi, lo;
        #pragma unroll
        for (int j = 0; j < 8; ++j) {
            _Float16 h = (_Float16)fv[j];
            hi[j] = h;
            lo[j] = (_Float16)(fv[j] - (float)h);
        }
        *(half8*)aDstHi = hi;
        *(half8*)aDstLo = lo;
        gl_lds16(bPtr[0], (void*)bDst[0]);
        gl_lds16(bPtr[1], (void*)bDst[1]);
        bPtr[0] += 32; bPtr[1] += 32;
        __syncthreads();
        if (kb + 1 < 16) {              // prefetch next A during compute
            int idx = (kb + 1) * 8 + kc * 2;
            pf0 = aBase[idx]; pf1 = aBase[idx + 1];
        }
        half8 ah[2], al[2];
        #pragma unroll
        for (int mi = 0; mi < 2; ++mi) { ah[mi] = *aHp[mi]; al[mi] = *aLp[mi]; }
        #pragma unroll
        for (int ni = 0; ni < 2; ++ni) {
            half8 bh = *bHp[ni];
            half8 bl = *bLp[ni];
            #pragma unroll
            for (int mi = 0; mi < 2; ++mi) acc[mi][ni] = MFMA_F16(ah[mi], bh, acc[mi][ni]);
            #pragma unroll
            for (int mi = 0; mi < 2; ++mi) acc[mi][ni] = MFMA_F16(ah[mi], bl, acc[mi][ni]);
            #pragma unroll
            for (int mi = 0; mi < 2; ++mi) acc[mi][ni] = MFMA_F16(al[mi], bh, acc[mi][ni]);
        }
        __syncthreads();
    }

    // epilogue: plain stores to slot buffer
    float* sOut = slot ? s1 : s0;
    float t = *tscp, iae = iav[e];
    float bv[2];
    #pragma unroll
    for (int ni = 0; ni < 2; ++ni) bv[ni] = bias[e * DM + n0 + c0 + ni * 16 + l15];
    #pragma unroll
    for (int mi = 0; mi < 2; ++mi) {
        int liBase = r0 + mi * 16 + q * 4;
        #pragma unroll
        for (int reg = 0; reg < 4; ++reg) {
            int li = liBase + reg;
            if (li < valid) {
                int tok = tokLds[li];
                float2 wp = wts[tok];
                float wgt = slot ? wp.y : wp.x;
                float sg = t * wgt * iae, sb = t * wgt;
                float* orow = sOut + (size_t)tok * DM + n0;
                #pragma unroll
                for (int ni = 0; ni < 2; ++ni)
                    orow[c0 + ni * 16 + l15] = acc[mi][ni][reg] * sg + bv[ni] * sb;
            }
        }
    }
}

// =============================== layer-1 GEMM (plain fp16, per-slot) ===============================
// A staged on-the-fly from fp32 h_emb with fused relu. KSTEP=64, KIT=8.
// bx: e=bx&7, nIdx=(bx>>3)&7, mt=bx>>6.
__global__ __launch_bounds__(256) void gemm1_kernel(
    const float* __restrict__ hsrc,
    const _Float16* __restrict__ Wh,
    const float* __restrict__ bias, const float* __restrict__ iav,
    const float* __restrict__ tscp,
    const int* __restrict__ cnt, const unsigned short* __restrict__ bkt,
    const float2* __restrict__ wts,
    int slot, int accum,
    float* __restrict__ outp)
{
    __shared__ __align__(16) _Float16 tA[64 * 64];
    __shared__ __align__(16) _Float16 tB[64 * 64];
    __shared__ int tokLds[64];

    int bx = blockIdx.x;
    int e = bx & 7, nIdx = (bx >> 3) & 7, mt = bx >> 6;
    int M = cnt[slot * 8 + e];
    int m0 = mt << 6;
    if (m0 >= M) return;
    int n0 = nIdx << 6;
    int valid = min(64, M - m0);
    int tid = threadIdx.x, lane = tid & 63, w = tid >> 6;
    const unsigned short* ob = bkt + (size_t)(slot * 8 + e) * NTOK;
    if (tid < 64) tokLds[tid] = ob[m0 + min(tid, valid - 1)];
    __syncthreads();

    floatx4 acc[2][2];
    #pragma unroll
    for (int mi = 0; mi < 2; ++mi)
        #pragma unroll
        for (int ni = 0; ni < 2; ++ni) acc[mi][ni] = (floatx4){0.f, 0.f, 0.f, 0.f};

    const _Float16* Wb = Wh + ((size_t)e * DM + n0) * DM;

    int subRow = lane >> 3, p = lane & 7;
    int cSt = p ^ (subRow & 7);
    const _Float16* bPtr[2]; _Float16* bDst[2];
    #pragma unroll
    for (int jj = 0; jj < 2; ++jj) {
        int j = w + jj * 4;
        int row = j * 8 + subRow;
        bPtr[jj] = Wb + (size_t)row * DM + cSt * 8;
        bDst[jj] = tB + j * 512;
    }
    // A staging: thread -> (row ar, chunk pair kc2): 4 float4 -> 2 half8 writes
    int ar = tid >> 2, kc2 = (tid & 3) * 2;
    const float4* aBase = (const float4*)(hsrc + (size_t)tokLds[ar] * DM);
    _Float16* aDst0 = tA + ar * 64 + ((kc2)     ^ (ar & 7)) * 8;
    _Float16* aDst1 = tA + ar * 64 + ((kc2 + 1) ^ (ar & 7)) * 8;

    int wm = w >> 1, wn = w & 1;
    int r0 = wm * 32, c0 = wn * 32;
    int q = lane >> 4, l15 = lane & 15;
    const half8 *aP0[2], *aP1[2], *bP0[2], *bP1[2];
    #pragma unroll
    for (int i = 0; i < 2; ++i) {
        int ra = r0 + i * 16 + l15;
        aP0[i] = (const half8*)(tA + ra * 64 + ((q)     ^ (ra & 7)) * 8);
        aP1[i] = (const half8*)(tA + ra * 64 + ((4 + q) ^ (ra & 7)) * 8);
        int rb = c0 + i * 16 + l15;
        bP0[i] = (const half8*)(tB + rb * 64 + ((q)     ^ (rb & 7)) * 8);
        bP1[i] = (const half8*)(tB + rb * 64 + ((4 + q) ^ (rb & 7)) * 8);
    }

    float4 pf[4];
    #pragma unroll
    for (int j = 0; j < 4; ++j) pf[j] = aBase[kc2 * 2 + j];
    for (int kb = 0; kb < 8; ++kb) {
        const float* fp = (const float*)pf;
        half8 h0v, h1v;
        #pragma unroll
        for (int j = 0; j < 8; ++j) h0v[j] = (_Float16)fmaxf(fp[j], 0.f);
        #pragma unroll
        for (int j = 0; j < 8; ++j) h1v[j] = (_Float16)fmaxf(fp[8 + j], 0.f);
        *(half8*)aDst0 = h0v;
        *(half8*)aDst1 = h1v;
        gl_lds16(bPtr[0], (void*)bDst[0]);
        gl_lds16(bPtr[1], (void*)bDst[1]);
        bPtr[0] += 64; bPtr[1] += 64;
        __syncthreads();
        if (kb + 1 < 8) {
            int idx = (kb + 1) * 16 + kc2 * 2;
            #pragma unroll
            for (int j = 0; j < 4; ++j) pf[j] = aBase[idx + j];
        }
        half8 a[2];
        #pragma unroll
        for (int mi = 0; mi < 2; ++mi) a[mi] = *aP0[mi];
        #pragma unroll
        for (int ni = 0; ni < 2; ++ni) {
            half8 b = *bP0[ni];
            #pragma unroll
            for (int mi = 0; mi < 2; ++mi) acc[mi][ni] = MFMA_F16(a[mi], b, acc[mi][ni]);
        }
        #pragma unroll
        for (int mi = 0; mi < 2; ++mi) a[mi] = *aP1[mi];
        #pragma unroll
        for (int ni = 0; ni < 2; ++ni) {
            half8 b = *bP1[ni];
            #pragma unroll
            for (int mi = 0; mi < 2; ++mi) acc[mi][ni] = MFMA_F16(a[mi], b, acc[mi][ni]);
        }
        __syncthreads();
    }

    float t = *tscp, iae = iav[e];
    float bv[2];
    #pragma unroll
    for (int ni = 0; ni < 2; ++ni) bv[ni] = bias[e * DM + n0 + c0 + ni * 16 + l15];
    #pragma unroll
    for (int mi = 0; mi < 2; ++mi) {
        int liBase = r0 + mi * 16 + q * 4;
        #pragma unroll
        for (int reg = 0; reg < 4; ++reg) {
            int li = liBase + reg;
            if (li < valid) {
                int tok = tokLds[li];
                float2 wp = wts[tok];
                float wgt = slot ? wp.y : wp.x;
                float sg = t * wgt * iae, sb = t * wgt;
                float* orow = outp + (size_t)tok * DM + n0;
                #pragma unroll
                for (int ni = 0; ni < 2; ++ni) {
                    float v = acc[mi][ni][reg] * sg + bv[ni] * sb;
                    int c = c0 + ni * 16 + l15;
                    if (accum) orow[c] += v; else orow[c] = v;
                }
            }
        }
    }
}

// =============================== finalize aux ===============================
__global__ void finalize_kernel(const float* __restrict__ ctrl, float* __restrict__ outp)
{
    if (threadIdx.x == 0) {
        float aux = 0.f;
        for (int l = 0; l < 2; ++l) {
            float vq = ctrl[48 + l] / (float)NTOK;
            float mean = 0.f;
            for (int e = 0; e < 8; ++e) mean += ctrl[32 + l * 8 + e];
            mean *= 0.125f;
            float s = 0.f;
            for (int e = 0; e < 8; ++e) {
                float d = ctrl[32 + l * 8 + e] - mean;
                s += d * d;
            }
            float var = s / 7.f;                       // ddof=1
            float lb = var / (mean * mean + 1e-10f);
            aux += 0.05f * vq + 0.01f * lb;
        }
        *outp = aux;
    }
}

// =============================== launch ===============================
extern "C" void kernel_launch(void* const* d_in, const int* in_sizes, int n_in,
                              void* d_out, int out_size, void* d_ws, size_t ws_size,
                              hipStream_t stream) {
    const float* x     = (const float*)d_in[0];
    const float* rm0   = (const float*)d_in[1];
    const float* W0    = (const float*)d_in[2];
    const float* b0    = (const float*)d_in[3];
    const float* temp0 = (const float*)d_in[4];
    const float* ca0   = (const float*)d_in[5];
    const float* rm1   = (const float*)d_in[6];
    const float* W1    = (const float*)d_in[7];
    const float* b1    = (const float*)d_in[8];
    const float* temp1 = (const float*)d_in[9];
    const float* ca1   = (const float*)d_in[10];
    float* out = (float*)d_out;

    char* ws = (char*)d_ws;
    float* ctrl = (float*)ws;
    int*   cnt  = (int*)ctrl;                 // [2][2][8]
    float* imp  = ctrl + 32;                  // [2][8]
    float* vq   = ctrl + 48;                  // [2]
    float* tsc  = ctrl + 50;                  // [2]
    float* ia   = ctrl + 52;                  // [2][8]
    float* rmn  = ctrl + 128;                 // [16][512]
    float2*        wts = (float2*)(ws + (size_t)64  * 1024);  // [2][16384]
    float2*        bs  = (float2*)(ws + (size_t)384 * 1024);  // [2][16384]
    unsigned char* key = (unsigned char*)(ws + (size_t)704 * 1024); // [2][2][16384]

    char* big = ws + (1 << 20);
    half4*          w0hi4 = (half4*)(big);                                 // 4MB
    half4*          w0lo4 = (half4*)(big + (size_t)4  * 1024 * 1024);      // 4MB
    half4*          w1h4  = (half4*)(big + (size_t)8  * 1024 * 1024);      // 4MB
    _Float16*       w0hi  = (_Float16*)w0hi4;
    _Float16*       w0lo  = (_Float16*)w0lo4;
    _Float16*       w1h   = (_Float16*)w1h4;
    unsigned short* bkt   = (unsigned short*)(big + (size_t)12 * 1024 * 1024); // 2MB
    // total ws use: 15MB

    float* s0 = out;                          // h0 region: s0 then h_emb
    float* s1 = out + (size_t)NTOK * DM;      // h1 region: s1 then h1

    prep_kernel<<<1, 256, 0, stream>>>(rm0, rm1, ca0, ca1, temp0, temp1, ctrl, rmn);
    conv_w_kernel<<<2048, 256, 0, stream>>>((const float4*)W0, (const float4*)W1,
                                            w0hi4, w0lo4, w1h4);

    // layer 0
    route0_kernel<<<4096, 256, 0, stream>>>(x, rmn, key, wts, bs);
    compact_kernel<<<16, 256, 0, stream>>>(key, wts, bs, cnt, bkt, imp, vq);
    gemm0_kernel<<<32768, 256, 0, stream>>>(x, w0hi, w0lo, b0, ia, tsc,
        cnt, bkt, wts, s0, s1);

    // layer 1: combine+route, then per-slot GEMMs (= then +=)
    route1_kernel<<<4096, 256, 0, stream>>>(s0, s1, s0, rmn + 4096,
        key + 2 * NTOK, wts + NTOK, bs + NTOK);
    compact_kernel<<<16, 256, 0, stream>>>(key + 2 * NTOK, wts + NTOK, bs + NTOK,
        cnt + 16, bkt + 16 * NTOK, imp + 8, vq + 1);
    gemm1_kernel<<<16384, 256, 0, stream>>>(s0, w1h, b1, ia + 8, tsc + 1,
        cnt + 16, bkt + 16 * NTOK, wts + NTOK, 0, 0, s1);
    gemm1_kernel<<<16384, 256, 0, stream>>>(s0, w1h, b1, ia + 8, tsc + 1,
        cnt + 16, bkt + 16 * NTOK, wts + NTOK, 1, 1, s1);

    finalize_kernel<<<1, 64, 0, stream>>>(ctrl, out + (size_t)2 * NTOK * DM);
}